// Round 6
// baseline (157.728 us; speedup 1.0000x reference)
//
#include <hip/hip_runtime.h>

#define Bdim 16
#define Sdim 16
#define Edim 256
#define Hdim 512
#define Vdim 16000
#define THR1f 0.8f
#define THR2f 1.0f

typedef unsigned int   u32;
typedef unsigned short u16;
typedef __attribute__((ext_vector_type(8)))  short bf16x8;
typedef __attribute__((ext_vector_type(16))) float f32x16;

__device__ __forceinline__ u16 f2bf(float f) {          // RNE fp32->bf16
  u32 u = __float_as_uint(f);
  return (u16)((u + 0x7FFFu + ((u >> 16) & 1u)) >> 16);
}
__device__ __forceinline__ u32 pack2(float a, float b) {
  return (u32)f2bf(a) | ((u32)f2bf(b) << 16);
}
__device__ __forceinline__ void gload16(const void* g, const void* lds) {
  __builtin_amdgcn_global_load_lds(
      (const __attribute__((address_space(1))) u32*)g,
      (__attribute__((address_space(3))) u32*)lds, 16, 0, 0);
}

// ---------------------------------------------------------------------------
// K1: cur1[r1=t*16+b][h] = emb_row(r1) @ fc1_w.T + fc1_b   (fp32, exact path)
// ---------------------------------------------------------------------------
__global__ __launch_bounds__(256) void snn_cur1(
    const int* __restrict__ x, const float* __restrict__ embed_w,
    const float* __restrict__ fc1_w, const float* __restrict__ fc1_b,
    float* __restrict__ cur1)
{
  __shared__ __align__(16) float As[64][68];
  __shared__ __align__(16) float Ws[64][68];
  __shared__ int sidx[64];
  const int tid = threadIdx.x;
  const int n0 = blockIdx.x * 64, r0 = blockIdx.y * 64;
  const int tx = tid & 15, ty = tid >> 4;

  if (tid < 64) {
    const int r1 = r0 + tid;                 // r1 = t*16 + b
    sidx[tid] = x[(r1 & 15) * Sdim + (r1 >> 4)];
  }

  float acc[4][4] = {{0.f}};
  for (int k0 = 0; k0 < Edim; k0 += 64) {
    __syncthreads();                         // also covers sidx on iter 0
#pragma unroll
    for (int i = 0; i < 16; ++i) {
      const int k = tid + i * 256;
      const int rr = k >> 6, j = k & 63;
      As[j][rr] = embed_w[(size_t)sidx[rr] * Edim + k0 + j];
      Ws[j][rr] = fc1_w[(size_t)(n0 + rr) * Edim + k0 + j];
    }
    __syncthreads();
#pragma unroll
    for (int j = 0; j < 64; ++j) {
      const float4 av = *(const float4*)&As[j][ty * 4];
      const float4 wv = *(const float4*)&Ws[j][tx * 4];
      const float a[4] = {av.x, av.y, av.z, av.w};
      const float w[4] = {wv.x, wv.y, wv.z, wv.w};
#pragma unroll
      for (int i = 0; i < 4; ++i)
#pragma unroll
        for (int jj = 0; jj < 4; ++jj)
          acc[i][jj] = fmaf(a[i], w[jj], acc[i][jj]);
    }
  }
#pragma unroll
  for (int i = 0; i < 4; ++i) {
    float4 o;
    o.x = acc[i][0] + fc1_b[n0 + tx * 4 + 0];
    o.y = acc[i][1] + fc1_b[n0 + tx * 4 + 1];
    o.z = acc[i][2] + fc1_b[n0 + tx * 4 + 2];
    o.w = acc[i][3] + fc1_b[n0 + tx * 4 + 3];
    *(float4*)&cur1[(size_t)(r0 + ty * 4 + i) * Hdim + n0 + tx * 4] = o;
  }
}

// ---------------------------------------------------------------------------
// K2: per-(b,h) m1 recurrence (fp32, exact); emits A in bf16 + mem1.
// ---------------------------------------------------------------------------
__global__ __launch_bounds__(256) void snn_rec(
    const float* __restrict__ cur1, const float* __restrict__ beta1p,
    const int* __restrict__ tsp, u16* __restrict__ Ab,
    float* __restrict__ mem1)
{
  const int id = blockIdx.x * 256 + threadIdx.x;   // 8192 threads
  const int b = id >> 9, h = id & 511;
  const float b1 = fminf(fmaxf(beta1p[0], 0.f), 1.f);
  const int T = tsp[0];

  double w9T = 1.0, w8T = 1.0;
  for (int i = 0; i < T; ++i) { w9T *= 0.9; w8T *= 0.8; }

  float m1 = 0.f;
  for (int t = 0; t < Sdim; ++t) {
    const float cur = cur1[(size_t)(t * Bdim + b) * Hdim + h];
    double p9 = w9T, p8 = w8T;                 // 0.9^{T-u}, 0.8^{T-u}
    float cs = 0.f, cm = 0.f;
    for (int u = 0; u < T; ++u) {
      const float reset = (m1 > THR1f) ? THR1f : 0.f;
      m1 = b1 * m1 + cur - reset;
      if (m1 > THR1f) {
        cs += (float)(p9 * (10.0 / 9.0));      // 0.9^{T-1-u}
        cm += (float)(10.0 * (p9 - p8));       // wm_u
      }
      p9 *= (10.0 / 9.0);
      p8 *= 1.25;
    }
    const size_t r = (size_t)(t * Bdim + b) * 2;
    Ab[r * Hdim + h]       = f2bf(cs);
    Ab[(r + 1) * Hdim + h] = f2bf(cm);
  }
  mem1[b * Hdim + h] = m1;
}

// ---------------------------------------------------------------------------
// K3: fused MFMA GEMM + Synaptic recurrence + spike output.  v2:
//  - 32x32x16 MFMA (halves LDS bytes/FLOP); 8 waves, wave wm owns rows
//    [wm*64, wm*64+64) x all 64 cols -> A read from LDS exactly once.
//  - double-buffered LDS, one barrier per K-step, loads issued pre-compute.
//  - token relay: wave wm handles t={2wm,2wm+1}; (s2,m2) handed to wm+1
//    through an 8KB LDS state buffer (8 barrier stages).
//  C-layout (m74/m101): col=lane&31, row=(reg&3)+8*(reg>>2)+4*(lane>>5);
//  row = 2b+c  ->  t=2wm+mi, b=j+4rq+2h, gs=acc[4rq+2j], gm=acc[4rq+2j+1].
// ---------------------------------------------------------------------------
__global__ __launch_bounds__(512, 2) void snn_fused(
    const u16* __restrict__ Ab, const float* __restrict__ W,
    const float* __restrict__ fc2_b, const int* __restrict__ tsp,
    float* __restrict__ out, float* __restrict__ syn2, float* __restrict__ mem2)
{
  __shared__ __align__(16) u16 AsBuf[2][512 * 64];   // 2 x 64 KB
  __shared__ __align__(16) u16 BsBuf[2][64 * 64];    // 2 x  8 KB
  __shared__ float2 stbuf[16 * 64];                  // 8 KB state relay
  const int tid  = threadIdx.x;          // 0..511
  const int lane = tid & 63;
  const int wm   = tid >> 6;             // wave id 0..7
  const int v0   = blockIdx.x * 64;

  f32x16 acc[2][2];                      // [mi][nj]
#pragma unroll
  for (int mi = 0; mi < 2; ++mi)
#pragma unroll
    for (int nj = 0; nj < 2; ++nj)
#pragma unroll
      for (int e = 0; e < 16; ++e) acc[mi][nj][e] = 0.f;

  // --- staging geometry ---
  // A: 8 rounds x (512thr x 16B) = 64KB; linear LDS dest, swizzled gsrc.
  // B: thread -> 8 W floats -> 8 bf16 (16B) at swizzled dest.
  const int brow = tid >> 3;                   // 0..63 (v-row)
  const int bk8  = (tid & 7) * 8;              // k-elem offset
  const int bdst = brow * 128 + (((tid & 7) * 16) ^ ((brow & 7) << 4));

#define STAGE_A(buf, k0s)                                                    \
  {                                                                          \
    _Pragma("unroll")                                                        \
    for (int rnd = 0; rnd < 8; ++rnd) {                                      \
      const int base = rnd * 8192 + (wm << 10);  /* wave-uniform */          \
      const int flat = base + lane * 16;                                     \
      const int row  = flat >> 7;                                            \
      const int cl   = (flat & 127) ^ ((row & 7) << 4);                      \
      gload16(Ab + ((size_t)row << 9) + (k0s) + (cl >> 1),                   \
              (char*)AsBuf[buf] + base);                                     \
    }                                                                        \
  }

  // ---- prologue: stage k0=0 into buf 0 ----
  STAGE_A(0, 0);
  {
    const float4* wp = (const float4*)&W[(size_t)(v0 + brow) * Hdim + bk8];
    const float4 wa = wp[0], wb = wp[1];
    uint4 o;
    o.x = pack2(wa.x, wa.y); o.y = pack2(wa.z, wa.w);
    o.z = pack2(wb.x, wb.y); o.w = pack2(wb.z, wb.w);
    *(uint4*)((char*)BsBuf[0] + bdst) = o;
  }
  __syncthreads();

  int c = 0;
  for (int k0 = 0; k0 < Hdim; k0 += 64) {
    float4 wa, wb;
    const bool pf = (k0 + 64 < Hdim);
    if (pf) {                               // issue next-tile loads FIRST
      STAGE_A(c ^ 1, k0 + 64);
      const float4* wp =
          (const float4*)&W[(size_t)(v0 + brow) * Hdim + (k0 + 64) + bk8];
      wa = wp[0]; wb = wp[1];
    }
    // ---- compute on buf c ----
    const int h16 = (lane >> 5) * 16;       // k-half byte offset
#pragma unroll
    for (int kk = 0; kk < 4; ++kk) {
      const int cb = kk * 32 + h16;
      bf16x8 bfr[2], afr[2];
#pragma unroll
      for (int nj = 0; nj < 2; ++nj) {
        const int br = nj * 32 + (lane & 31);
        bfr[nj] = *(const bf16x8*)((char*)BsBuf[c] + br * 128 +
                                   (cb ^ ((br & 7) << 4)));
      }
#pragma unroll
      for (int mi = 0; mi < 2; ++mi) {
        const int ar = wm * 64 + mi * 32 + (lane & 31);
        afr[mi] = *(const bf16x8*)((char*)AsBuf[c] + ar * 128 +
                                   (cb ^ ((ar & 7) << 4)));
      }
#pragma unroll
      for (int mi = 0; mi < 2; ++mi)
#pragma unroll
        for (int nj = 0; nj < 2; ++nj)
          acc[mi][nj] = __builtin_amdgcn_mfma_f32_32x32x16_bf16(
              afr[mi], bfr[nj], acc[mi][nj], 0, 0, 0);
    }
    if (pf) {                               // finish B: cvt + swizzled write
      uint4 o;
      o.x = pack2(wa.x, wa.y); o.y = pack2(wa.z, wa.w);
      o.z = pack2(wb.x, wb.y); o.w = pack2(wb.z, wb.w);
      *(uint4*)((char*)BsBuf[c ^ 1] + bdst) = o;
    }
    __syncthreads();                        // drains vmcnt+lgkmcnt
    c ^= 1;
  }

  // ---- epilogue: relayed Synaptic recurrence + spikes ----
  const int T = tsp[0];
  double p9 = 1.0, p8 = 1.0;
  for (int i = 0; i < T; ++i) { p9 *= 0.9; p8 *= 0.8; }
  const float Ps  = (float)p9;                       // 0.9^T
  const float Pm  = (float)p8;                       // 0.8^T
  const float Pms = (float)(0.9 * 10.0 * (p9 - p8)); // s2-coeff into m2
  const float Sws = (float)(10.0 * (1.0 - p9));
  const float Swm = (float)(10.0 * (9.0 * (1.0 - p9) - 4.0 * (1.0 - p8)));

  const int h  = lane >> 5;
  const int vl = lane & 31;
  float bbs[2], bbm[2];
#pragma unroll
  for (int nj = 0; nj < 2; ++nj) {
    const float bb = fc2_b[v0 + nj * 32 + vl];
    bbs[nj] = bb * Sws;
    bbm[nj] = bb * Swm;
  }

  float s2[2][8], m2[2][8];                // [nj][rq*2+j]
  for (int s = 0; s < 8; ++s) {
    if (wm == s) {
#pragma unroll
      for (int nj = 0; nj < 2; ++nj)
#pragma unroll
        for (int rq = 0; rq < 4; ++rq)
#pragma unroll
          for (int j = 0; j < 2; ++j) {
            const int b = j + 4 * rq + 2 * h;
            if (s > 0) {
              const float2 st = stbuf[b * 64 + nj * 32 + vl];
              s2[nj][rq * 2 + j] = st.x; m2[nj][rq * 2 + j] = st.y;
            } else {
              s2[nj][rq * 2 + j] = 0.f; m2[nj][rq * 2 + j] = 0.f;
            }
          }
#pragma unroll
      for (int mi = 0; mi < 2; ++mi) {     // t = 2s + mi
        const int t = 2 * s + mi;
#pragma unroll
        for (int nj = 0; nj < 2; ++nj)
#pragma unroll
          for (int rq = 0; rq < 4; ++rq)
#pragma unroll
            for (int j = 0; j < 2; ++j) {
              const int b  = j + 4 * rq + 2 * h;
              const int si = rq * 2 + j;
              const float gs = acc[mi][nj][4 * rq + 2 * j];
              const float gm = acc[mi][nj][4 * rq + 2 * j + 1];
              const float m2n =
                  Pm * m2[nj][si] + Pms * s2[nj][si] + gm + bbm[nj];
              s2[nj][si] = Ps * s2[nj][si] + gs + bbs[nj];
              m2[nj][si] = m2n;
              out[((size_t)b * Sdim + t) * Vdim + v0 + nj * 32 + vl] =
                  (m2n > THR2f) ? 1.f : 0.f;
            }
      }
#pragma unroll
      for (int nj = 0; nj < 2; ++nj)
#pragma unroll
        for (int rq = 0; rq < 4; ++rq)
#pragma unroll
          for (int j = 0; j < 2; ++j) {
            const int b  = j + 4 * rq + 2 * h;
            const int si = rq * 2 + j;
            if (s < 7) {
              stbuf[b * 64 + nj * 32 + vl] =
                  make_float2(s2[nj][si], m2[nj][si]);
            } else {
              syn2[(size_t)b * Vdim + v0 + nj * 32 + vl] = s2[nj][si];
              mem2[(size_t)b * Vdim + v0 + nj * 32 + vl] = m2[nj][si];
            }
          }
    }
    __syncthreads();
  }
}

// ---------------------------------------------------------------------------
extern "C" void kernel_launch(void* const* d_in, const int* in_sizes, int n_in,
                              void* d_out, int out_size, void* d_ws, size_t ws_size,
                              hipStream_t stream) {
  const int*   x       = (const int*)d_in[0];
  const float* embed_w = (const float*)d_in[1];
  const float* fc1_w   = (const float*)d_in[2];
  const float* fc1_b   = (const float*)d_in[3];
  const float* fc2_w   = (const float*)d_in[4];
  const float* fc2_b   = (const float*)d_in[5];
  const float* beta1   = (const float*)d_in[6];
  const int*   tsteps  = (const int*)d_in[7];

  float* out  = (float*)d_out;                          // [16][16][16000]
  float* mem1 = out + (size_t)Bdim * Sdim * Vdim;       // [16][512]
  float* syn2 = mem1 + (size_t)Bdim * Hdim;             // [16][16000]
  float* mem2 = syn2 + (size_t)Bdim * Vdim;             // [16][16000]

  // ws: cur1 512 KB + Ab 512 KB = 1 MB
  float* cur1 = (float*)d_ws;
  u16*   Ab   = (u16*)((char*)d_ws + 524288);

  snn_cur1<<<dim3(Hdim / 64, (Sdim * Bdim) / 64), 256, 0, stream>>>(
      x, embed_w, fc1_w, fc1_b, cur1);
  snn_rec<<<(Bdim * Hdim) / 256, 256, 0, stream>>>(cur1, beta1, tsteps, Ab, mem1);
  snn_fused<<<Vdim / 64, 512, 0, stream>>>(Ab, fc2_w, fc2_b, tsteps,
                                           out, syn2, mem2);
}